// Round 9
// baseline (250.341 us; speedup 1.0000x reference)
//
#include <hip/hip_runtime.h>
#include <hip/hip_bf16.h>

// AttentionHead: B=4, T=2048, C=1024, hs=64. All fp32 in/out.
#define D_MODEL 1024
#define HS 64
#define T_LEN 2048
#define JCH 512          // j-chunk width per attention block
#define NCH 4            // max chunks per row = T_LEN/JCH

typedef __attribute__((ext_vector_type(8))) short bf16x8;   // MFMA A/B frag
typedef __attribute__((ext_vector_type(4))) float f32x4;    // MFMA C/D frag

// split 8 floats into hi/lo bf16 (truncation split: residual exact)
__device__ inline void split8(const float* v, int4& hi, int4& lo) {
    union { unsigned short u[8]; int4 v4; } uh, ul;
    #pragma unroll
    for (int i = 0; i < 8; ++i) {
        const unsigned int b = __float_as_uint(v[i]);
        const unsigned short h = (unsigned short)(b >> 16);
        const float r = v[i] - __uint_as_float((unsigned int)h << 16);
        uh.u[i] = h;
        ul.u[i] = (unsigned short)(__float_as_uint(r) >> 16);
    }
    hi = uh.v4; lo = ul.v4;
}

// fp32 -> bf16 round-to-nearest-even (finite inputs only here)
__device__ inline unsigned short f2bf_rne(float f) {
    const unsigned int b = __float_as_uint(f);
    return (unsigned short)((b + 0x7FFFu + ((b >> 16) & 1u)) >> 16);
}
__device__ inline float bf2f(unsigned short h) {
    return __uint_as_float((unsigned int)h << 16);
}

// ---------------------------------------------------------------------------
// Kernel 0: W prep (coalesced) — UNCHANGED (passing).
// ---------------------------------------------------------------------------
__global__ __launch_bounds__(256) void wprep_kernel(
    const float* __restrict__ Wq, const float* __restrict__ Wk,
    const float* __restrict__ Wv, short* __restrict__ Wh, short* __restrict__ Wl)
{
    __shared__ float tile[64][69];
    const int tid = threadIdx.x;
    const int kb = blockIdx.x & 15;       // k-block 0..15
    const int m  = blockIdx.x >> 4;       // matrix 0..2
    const float* W = (m == 0) ? Wq : (m == 1) ? Wk : Wv;
    #pragma unroll
    for (int it = 0; it < 4; ++it) {
        const int idx = tid + 256 * it;
        const int kr = idx >> 4, c4 = idx & 15;
        *(float4*)&tile[kr][4 * c4] =
            *(const float4*)(W + (size_t)(kb * 64 + kr) * HS + 4 * c4);
    }
    __syncthreads();
    #pragma unroll
    for (int it = 0; it < 2; ++it) {
        const int s = tid + 256 * it;     // 0..511
        const int n = s >> 3, kc = s & 7;
        float v[8];
        #pragma unroll
        for (int i = 0; i < 8; ++i) v[i] = tile[kc * 8 + i][n];
        int4 hi, lo;
        split8(v, hi, lo);
        const size_t off = (size_t)(m * 64 + n) * D_MODEL + kb * 64 + kc * 8;
        *(int4*)(Wh + off) = hi;
        *(int4*)(Wl + off) = lo;
    }
}

// ---------------------------------------------------------------------------
// Kernel 1: QKV projection via split-bf16 MFMA.
// Block: 128 threads (2 waves), tile 16 M x 96 N; grid (BT/16, 2) = 1024
// blocks -> 4 independent barrier-domains per CU (round 8 was grid-limited
// to 2). Wave = 1 Mtile x 3 Ntiles. K=32 chunks, register-prefetch pipeline.
// ---------------------------------------------------------------------------
__global__ __launch_bounds__(128, 2) void qkv_kernel(
    const float* __restrict__ x,
    const short* __restrict__ Wh, const short* __restrict__ Wl,
    const float* __restrict__ bq, const float* __restrict__ bk,
    float* __restrict__ q, float* __restrict__ k, float* __restrict__ vt, int BT)
{
    __shared__ __align__(16) short Ah[520], Al[520];          // 1 Mtile
    __shared__ __align__(16) short Bh[6 * 520], Bl[6 * 520];  // 6 Ntiles

    const int tid  = threadIdx.x;
    const int r0   = blockIdx.x * 16;
    const int nb   = blockIdx.y;          // N-half: global cols 96*nb ..
    const int wave = tid >> 6;            // 0..1
    const int lane = tid & 63;
    const int nt0  = wave * 3;            // wave's first ntile

    f32x4 acc[3];
    #pragma unroll
    for (int j = 0; j < 3; ++j) acc[j] = (f32x4)(0.f);

    // staging roles:
    //  A (64 slots, 1 Mtile): wave 0, slot = lane. row = lane&15, kc = lane>>4.
    //  B (6 ntiles x 64 slots): wave 0 -> ntiles {0,1}; wave 1 -> ntiles {2..5}.
    const float* axsrc =
        x + (size_t)(r0 + (lane & 15)) * D_MODEL + (lane >> 4) * 8;

    size_t boff[4];
    const int nB = wave ? 4 : 2;
    #pragma unroll
    for (int i = 0; i < 4; ++i) {
        const int ntb = wave ? (2 + i) : i;
        boff[i] = (size_t)(nb * 96 + ntb * 16 + (lane & 15)) * D_MODEL + (lane >> 4) * 8;
    }

    // preload k0 = 0
    float4 a0v, a1v;
    int4 pbh[4], pbl[4];
    if (wave == 0) {
        a0v = *(const float4*)(axsrc);
        a1v = *(const float4*)(axsrc + 4);
    }
    #pragma unroll
    for (int i = 0; i < 4; ++i)
        if (i < nB) {
            pbh[i] = *(const int4*)(Wh + boff[i]);
            pbl[i] = *(const int4*)(Wl + boff[i]);
        }

    for (int k0 = 0; k0 < D_MODEL; k0 += 32) {
        __syncthreads();                  // prior iteration's LDS readers done
        // ---- write staged registers to LDS
        if (wave == 0) {
            float xv[8];
            *(float4*)&xv[0] = a0v;
            *(float4*)&xv[4] = a1v;
            int4 hi, lo;
            split8(xv, hi, lo);
            *(int4*)&Ah[lane * 8] = hi;
            *(int4*)&Al[lane * 8] = lo;
        }
        #pragma unroll
        for (int i = 0; i < 4; ++i)
            if (i < nB) {
                const int ntb = wave ? (2 + i) : i;
                *(int4*)&Bh[ntb * 520 + lane * 8] = pbh[i];
                *(int4*)&Bl[ntb * 520 + lane * 8] = pbl[i];
            }
        __syncthreads();                  // LDS ready
        // ---- preload next k-chunk (latency hides under MFMA below)
        const int kn = k0 + 32;
        if (kn < D_MODEL) {
            if (wave == 0) {
                a0v = *(const float4*)(axsrc + kn);
                a1v = *(const float4*)(axsrc + kn + 4);
            }
            #pragma unroll
            for (int i = 0; i < 4; ++i)
                if (i < nB) {
                    pbh[i] = *(const int4*)(Wh + boff[i] + kn);
                    pbl[i] = *(const int4*)(Wl + boff[i] + kn);
                }
        }
        // ---- MFMA: 1 Mtile x 3 Ntiles x 3 split passes
        const bf16x8 afh = *(const bf16x8*)&Ah[lane * 8];
        const bf16x8 afl = *(const bf16x8*)&Al[lane * 8];
        #pragma unroll
        for (int j = 0; j < 3; ++j) {
            const int nt = nt0 + j;
            const bf16x8 bfh = *(const bf16x8*)&Bh[nt * 520 + lane * 8];
            const bf16x8 bfl = *(const bf16x8*)&Bl[nt * 520 + lane * 8];
            acc[j] = __builtin_amdgcn_mfma_f32_16x16x32_bf16(afh, bfh, acc[j], 0, 0, 0);
            acc[j] = __builtin_amdgcn_mfma_f32_16x16x32_bf16(afh, bfl, acc[j], 0, 0, 0);
            acc[j] = __builtin_amdgcn_mfma_f32_16x16x32_bf16(afl, bfh, acc[j], 0, 0, 0);
        }
    }

    // ---- epilogue: C/D layout col=lane&15, row=(lane>>4)*4+reg
    const int rowb = r0 + (lane >> 4) * 4;
    #pragma unroll
    for (int j = 0; j < 3; ++j) {
        const int c = nb * 96 + (nt0 + j) * 16 + (lane & 15);
        if (c < 64) {
            const float bias = bq[c];
            #pragma unroll
            for (int r = 0; r < 4; ++r)
                q[(size_t)(rowb + r) * HS + c] = acc[j][r] + bias;
        } else if (c < 128) {
            const float bias = bk[c - 64];
            #pragma unroll
            for (int r = 0; r < 4; ++r)
                k[(size_t)(rowb + r) * HS + (c - 64)] = acc[j][r] + bias;
        } else {
            float4 o;
            o.x = acc[j][0]; o.y = acc[j][1]; o.z = acc[j][2]; o.w = acc[j][3];
            *(float4*)(vt + (size_t)(c - 128) * BT + rowb) = o;
        }
    }
}

// ---------------------------------------------------------------------------
// Kernel 2: flash-style attention via MFMA.
// Block: 128 threads (2 waves x 16 q-rows = 32-row Q-tile), grid (BT/32, 4)
// -> ~640 live causal blocks (was 320). Next K/V tile register-prefetched
// after the compute barrier (global latency hides under QK^T/softmax/PV).
// Math order identical to round 8 -> bit-identical output.
// ---------------------------------------------------------------------------
__global__ __launch_bounds__(128) void attn_kernel(
    const float* __restrict__ q_ws, const float* __restrict__ k_ws,
    const float* __restrict__ vt_ws, const int* __restrict__ maskp,
    float* __restrict__ part_O, float* __restrict__ part_ml, int BT)
{
    __shared__ __align__(16) short Kh[4096], Kl[4096];
    __shared__ __align__(16) short Vt[4096];
    __shared__ __align__(16) short Pl[2][16 * 72];

    const int tile  = blockIdx.x;
    const int chunk = blockIdx.y;
    const int r0 = tile * 32;
    const int tb = r0 / T_LEN;
    const int t0 = r0 - tb * T_LEN;
    const int mask = (*maskp != 0);
    const int n_max = mask ? (t0 + 32) : T_LEN;
    const int j0 = chunk * JCH;
    if (j0 >= n_max) return;            // dead block (combine never reads it)
    const int hi_j = min(j0 + JCH, n_max);
    const int njt = (hi_j - j0 + 63) >> 6;

    const int tid  = threadIdx.x;
    const int w    = tid >> 6;
    const int lane = tid & 63;
    const int quad = lane >> 4;
    const int l15  = lane & 15;
    const int rw0  = t0 + 16 * w;
    const int rowa = r0 + 16 * w + quad * 4;

    // Q fragments direct from global (loop-invariant), split bf16
    bf16x8 qfh[2], qfl[2];
    {
        const float* qrow = q_ws + (size_t)(r0 + 16 * w + l15) * HS + quad * 8;
        #pragma unroll
        for (int kc = 0; kc < 2; ++kc) {
            float v[8];
            *(float4*)&v[0] = *(const float4*)(qrow + kc * 32);
            *(float4*)&v[4] = *(const float4*)(qrow + kc * 32 + 4);
            union { int4 i; bf16x8 b; } ch, cl;
            split8(v, ch.i, cl.i);
            qfh[kc] = ch.b;
            qfl[kc] = cl.b;
        }
    }

    f32x4 oacc[4];
    #pragma unroll
    for (int nt = 0; nt < 4; ++nt) oacc[nt] = (f32x4)(0.f);
    float m_r[4] = {-INFINITY, -INFINITY, -INFINITY, -INFINITY};
    float l_r[4] = {0.f, 0.f, 0.f, 0.f};

    const float* kbase = k_ws + (size_t)tb * T_LEN * HS;
    const float* vbase = vt_ws + (size_t)tb * T_LEN;   // + n*BT + jcol

    // staging slot geometry (s in [0,512), 4 slots/thread)
    //  K: sc=s>>6: jsub=sc>>1, kc=sc&1; ls=s&63: jrow=+jsub*16+(ls&15), koff=kc*32+(ls>>4)*8
    //  V: sc=s>>6: jc=sc>>2, nt=sc&3;  ls=s&63: n=nt*16+(ls&15), jcol=+jc*32+(ls>>4)*8
    float4 pKa[4], pKb[4], pVa[4], pVb[4];
    auto load_tiles = [&](int jb) {
        #pragma unroll
        for (int it = 0; it < 4; ++it) {
            const int s  = tid + 128 * it;
            const int ls = s & 63;
            const int sc = s >> 6;
            {
                const int jsub = sc >> 1, kc = sc & 1;
                const float* src = kbase + (size_t)(jb + jsub * 16 + (ls & 15)) * HS
                                         + kc * 32 + (ls >> 4) * 8;
                pKa[it] = *(const float4*)src;
                pKb[it] = *(const float4*)(src + 4);
            }
            {
                const int jc = sc >> 2, nt = sc & 3;
                const float* src = vbase + (size_t)(nt * 16 + (ls & 15)) * BT
                                         + jb + jc * 32 + (ls >> 4) * 8;
                pVa[it] = *(const float4*)src;
                pVb[it] = *(const float4*)(src + 4);
            }
        }
    };

    load_tiles(j0);   // preload first tile

    for (int jt = 0; jt < njt; ++jt) {
        const int jbase = j0 + jt * 64;
        __syncthreads();   // prior tile's LDS readers done
        // ---- write prefetched K (split) and V (RNE bf16) to LDS
        #pragma unroll
        for (int it = 0; it < 4; ++it) {
            const int s = tid + 128 * it;
            {
                float v[8];
                *(float4*)&v[0] = pKa[it];
                *(float4*)&v[4] = pKb[it];
                int4 hi, lo;
                split8(v, hi, lo);
                *(int4*)&Kh[s * 8] = hi;
                *(int4*)&Kl[s * 8] = lo;
            }
            {
                float v[8];
                *(float4*)&v[0] = pVa[it];
                *(float4*)&v[4] = pVb[it];
                union { unsigned short u[8]; int4 i; } pk;
                #pragma unroll
                for (int i = 0; i < 8; ++i) pk.u[i] = f2bf_rne(v[i]);
                *(int4*)&Vt[s * 8] = pk.i;
            }
        }
        __syncthreads();
        // ---- prefetch next tile (clamped re-read on last iteration)
        load_tiles((jt + 1 < njt) ? (jbase + 64) : jbase);

        const bool active = (!mask) || (jbase <= rw0 + 15);
        if (active) {
            // ---- QK^T: 4 j-subtiles x (2 k-chunks x 3 split passes)
            f32x4 sacc[4];
            #pragma unroll
            for (int jsub = 0; jsub < 4; ++jsub) {
                f32x4 s = (f32x4)(0.f);
                #pragma unroll
                for (int kc = 0; kc < 2; ++kc) {
                    const bf16x8 kh = *(const bf16x8*)&Kh[((jsub * 2 + kc) * 64 + lane) * 8];
                    const bf16x8 kl = *(const bf16x8*)&Kl[((jsub * 2 + kc) * 64 + lane) * 8];
                    s = __builtin_amdgcn_mfma_f32_16x16x32_bf16(qfh[kc], kh, s, 0, 0, 0);
                    s = __builtin_amdgcn_mfma_f32_16x16x32_bf16(qfh[kc], kl, s, 0, 0, 0);
                    s = __builtin_amdgcn_mfma_f32_16x16x32_bf16(qfl[kc], kh, s, 0, 0, 0);
                }
                sacc[jsub] = s;
            }
            // ---- mask + scale + row max (C-layout: row=quad*4+r, col=l15)
            float sval[4][4], rmax[4];
            #pragma unroll
            for (int r = 0; r < 4; ++r) rmax[r] = -INFINITY;
            #pragma unroll
            for (int jsub = 0; jsub < 4; ++jsub) {
                const int jg = jbase + jsub * 16 + l15;
                #pragma unroll
                for (int r = 0; r < 4; ++r) {
                    const int tg = rw0 + quad * 4 + r;
                    const float vv = (mask && (jg > tg)) ? -INFINITY : 8.0f * sacc[jsub][r];
                    sval[jsub][r] = vv;
                    rmax[r] = fmaxf(rmax[r], vv);
                }
            }
            #pragma unroll
            for (int d = 1; d < 16; d <<= 1)
                #pragma unroll
                for (int r = 0; r < 4; ++r)
                    rmax[r] = fmaxf(rmax[r], __shfl_xor(rmax[r], d));
            float alpha[4], msafe[4];
            #pragma unroll
            for (int r = 0; r < 4; ++r) {
                const float mn = fmaxf(m_r[r], rmax[r]);
                msafe[r] = (mn == -INFINITY) ? 0.f : mn;
                alpha[r] = __expf(m_r[r] - msafe[r]);   // -inf -> 0, never NaN
                m_r[r] = mn;
            }
            // ---- exp -> bf16 P (wave-private LDS) + consistent l sums
            short* Pw = &Pl[w][0];
            float rsum[4] = {0.f, 0.f, 0.f, 0.f};
            #pragma unroll
            for (int jsub = 0; jsub < 4; ++jsub) {
                #pragma unroll
                for (int r = 0; r < 4; ++r) {
                    const float e = __expf(sval[jsub][r] - msafe[r]);
                    const unsigned short eb = f2bf_rne(e);
                    Pw[(quad * 4 + r) * 72 + jsub * 16 + l15] = (short)eb;
                    rsum[r] += bf2f(eb);
                }
            }
            #pragma unroll
            for (int d = 1; d < 16; d <<= 1)
                #pragma unroll
                for (int r = 0; r < 4; ++r)
                    rsum[r] += __shfl_xor(rsum[r], d);
            #pragma unroll
            for (int r = 0; r < 4; ++r)
                l_r[r] = l_r[r] * alpha[r] + rsum[r];
            // ---- rescale O, then PV (P A-frags read back from LDS)
            #pragma unroll
            for (int nt = 0; nt < 4; ++nt)
                #pragma unroll
                for (int r = 0; r < 4; ++r)
                    oacc[nt][r] *= alpha[r];
            bf16x8 pf[2];
            #pragma unroll
            for (int jc = 0; jc < 2; ++jc)
                pf[jc] = *(const bf16x8*)&Pw[l15 * 72 + jc * 32 + quad * 8];
            #pragma unroll
            for (int nt = 0; nt < 4; ++nt) {
                #pragma unroll
                for (int jc = 0; jc < 2; ++jc) {
                    const bf16x8 vf = *(const bf16x8*)&Vt[((jc * 4 + nt) * 64 + lane) * 8];
                    oacc[nt] = __builtin_amdgcn_mfma_f32_16x16x32_bf16(pf[jc], vf, oacc[nt], 0, 0, 0);
                }
            }
        }
    }

    // ---- epilogue: write partials (C-layout rows)
    #pragma unroll
    for (int nt = 0; nt < 4; ++nt)
        #pragma unroll
        for (int r = 0; r < 4; ++r)
            part_O[((size_t)(rowa + r) * NCH + chunk) * HS + nt * 16 + l15] = oacc[nt][r];
    if (l15 == 0) {
        #pragma unroll
        for (int r = 0; r < 4; ++r) {
            float2 ml;
            ml.x = m_r[r];
            ml.y = l_r[r];
            *(float2*)(part_ml + ((size_t)(rowa + r) * NCH + chunk) * 2) = ml;
        }
    }
}

// ---------------------------------------------------------------------------
// Kernel 3: combine chunk partials — UNCHANGED (passing).
// ---------------------------------------------------------------------------
__global__ __launch_bounds__(256) void combine_kernel(
    const float* __restrict__ part_O, const float* __restrict__ part_ml,
    const int* __restrict__ maskp, float* __restrict__ out)
{
    const int f = blockIdx.x * 256 + threadIdx.x;
    const int row = f >> 6;
    const int d = f & 63;
    const int t = row & (T_LEN - 1);
    const int mask = (*maskp != 0);
    const int n = mask ? (t + 1) : T_LEN;
    const int nc = (n + JCH - 1) / JCH;

    float mv[NCH], lv[NCH];
    float M = -INFINITY;
    for (int c = 0; c < nc; ++c) {
        const float2 ml = *(const float2*)(part_ml + ((size_t)row * NCH + c) * 2);
        mv[c] = ml.x; lv[c] = ml.y;
        M = fmaxf(M, ml.x);
    }
    float L = 0.f, O = 0.f;
    for (int c = 0; c < nc; ++c) {
        const float w = __expf(mv[c] - M);
        L += lv[c] * w;
        O = fmaf(part_O[((size_t)row * NCH + c) * HS + d], w, O);
    }
    out[(size_t)row * HS + d] = O / L;
}

// ---------------------------------------------------------------------------
extern "C" void kernel_launch(void* const* d_in, const int* in_sizes, int n_in,
                              void* d_out, int out_size, void* d_ws, size_t ws_size,
                              hipStream_t stream) {
    const float* x  = (const float*)d_in[0];
    const float* Wq = (const float*)d_in[1];
    const float* bq = (const float*)d_in[2];
    const float* Wk = (const float*)d_in[3];
    const float* bk = (const float*)d_in[4];
    const float* Wv = (const float*)d_in[5];
    const int* maskp = (const int*)d_in[6];

    const int BT = in_sizes[0] / D_MODEL;   // 8192

    // ws layout (floats): q,k [BT*64], vt [64*BT], part_O [BT*4*64], part_ml [BT*4*2]
    float* q   = (float*)d_ws;
    float* k   = q + (size_t)BT * HS;
    float* vt  = k + (size_t)BT * HS;
    float* pO  = vt + (size_t)BT * HS;
    float* pml = pO + (size_t)BT * NCH * HS;

    // W split buffers ALIAS part_O (dead until attn_kernel runs, stream-ordered)
    short* Wh = (short*)pO;
    short* Wl = Wh + (size_t)192 * D_MODEL;

    wprep_kernel<<<48, 256, 0, stream>>>(Wq, Wk, Wv, Wh, Wl);
    dim3 qgrid(BT / 16, 2);
    qkv_kernel<<<qgrid, 128, 0, stream>>>(x, Wh, Wl, bq, bk, q, k, vt, BT);
    dim3 agrid(BT / 32, NCH);
    attn_kernel<<<agrid, 128, 0, stream>>>(q, k, vt, maskp, pO, pml, BT);
    combine_kernel<<<(BT * HS) / 256, 256, 0, stream>>>(pO, pml, maskp, (float*)d_out);
}

// Round 10
// 195.340 us; speedup vs baseline: 1.2816x; 1.2816x over previous
//
#include <hip/hip_runtime.h>
#include <hip/hip_bf16.h>

// AttentionHead: B=4, T=2048, C=1024, hs=64. All fp32 in/out.
#define D_MODEL 1024
#define HS 64
#define T_LEN 2048
#define JCH 512          // j-chunk width per attention block
#define NCH 4            // max chunks per row = T_LEN/JCH

typedef __attribute__((ext_vector_type(8))) short bf16x8;   // MFMA A/B frag
typedef __attribute__((ext_vector_type(4))) float f32x4;    // MFMA C/D frag

// split 8 floats into hi/lo bf16 (truncation split: residual exact)
__device__ inline void split8(const float* v, int4& hi, int4& lo) {
    union { unsigned short u[8]; int4 v4; } uh, ul;
    #pragma unroll
    for (int i = 0; i < 8; ++i) {
        const unsigned int b = __float_as_uint(v[i]);
        const unsigned short h = (unsigned short)(b >> 16);
        const float r = v[i] - __uint_as_float((unsigned int)h << 16);
        uh.u[i] = h;
        ul.u[i] = (unsigned short)(__float_as_uint(r) >> 16);
    }
    hi = uh.v4; lo = ul.v4;
}

// fp32 -> bf16 round-to-nearest-even (finite inputs only here)
__device__ inline unsigned short f2bf_rne(float f) {
    const unsigned int b = __float_as_uint(f);
    return (unsigned short)((b + 0x7FFFu + ((b >> 16) & 1u)) >> 16);
}
__device__ inline float bf2f(unsigned short h) {
    return __uint_as_float((unsigned int)h << 16);
}

// ---------------------------------------------------------------------------
// Kernel 0: W prep (coalesced) — UNCHANGED (passing).
// ---------------------------------------------------------------------------
__global__ __launch_bounds__(256) void wprep_kernel(
    const float* __restrict__ Wq, const float* __restrict__ Wk,
    const float* __restrict__ Wv, short* __restrict__ Wh, short* __restrict__ Wl)
{
    __shared__ float tile[64][69];
    const int tid = threadIdx.x;
    const int kb = blockIdx.x & 15;       // k-block 0..15
    const int m  = blockIdx.x >> 4;       // matrix 0..2
    const float* W = (m == 0) ? Wq : (m == 1) ? Wk : Wv;
    #pragma unroll
    for (int it = 0; it < 4; ++it) {
        const int idx = tid + 256 * it;
        const int kr = idx >> 4, c4 = idx & 15;
        *(float4*)&tile[kr][4 * c4] =
            *(const float4*)(W + (size_t)(kb * 64 + kr) * HS + 4 * c4);
    }
    __syncthreads();
    #pragma unroll
    for (int it = 0; it < 2; ++it) {
        const int s = tid + 256 * it;     // 0..511
        const int n = s >> 3, kc = s & 7;
        float v[8];
        #pragma unroll
        for (int i = 0; i < 8; ++i) v[i] = tile[kc * 8 + i][n];
        int4 hi, lo;
        split8(v, hi, lo);
        const size_t off = (size_t)(m * 64 + n) * D_MODEL + kb * 64 + kc * 8;
        *(int4*)(Wh + off) = hi;
        *(int4*)(Wl + off) = lo;
    }
}

// ---------------------------------------------------------------------------
// Kernel 1: QKV projection via split-bf16 MFMA.
// Grid (BT/32, 3) = 768 blocks x 256 threads -> 3 blocks/CU (round 8 was
// grid-limited to 2). Tile 32 M x 64 N; wave = 1 Mtile x 2 Ntiles.
// Column slice nb aligns exactly with q / k / vt so every 128B store line
// is written by one block (round 9's 16-row/96-col split caused 15x HBM
// write amplification — WRITE_SIZE 6->95 MB — via cross-block partial lines).
// 2-deep register prefetch: loads issued at iter i are consumed at i+2.
// ---------------------------------------------------------------------------
__global__ __launch_bounds__(256, 2) void qkv_kernel(
    const float* __restrict__ x,
    const short* __restrict__ Wh, const short* __restrict__ Wl,
    const float* __restrict__ bq, const float* __restrict__ bk,
    float* __restrict__ q, float* __restrict__ k, float* __restrict__ vt, int BT)
{
    __shared__ __align__(16) short Ah[2 * 520], Al[2 * 520];   // 2 Mtiles
    __shared__ __align__(16) short Bh[4 * 520], Bl[4 * 520];   // 4 Ntiles

    const int tid  = threadIdx.x;
    const int r0   = blockIdx.x * 32;
    const int nb   = blockIdx.y;          // col slice: global cols 64*nb ..
    const int wave = tid >> 6;
    const int lane = tid & 63;
    const int mt_w = wave >> 1;           // wave's Mtile (0..1)
    const int nt0  = (wave & 1) * 2;      // wave's first local ntile

    f32x4 acc[2];
    acc[0] = (f32x4)(0.f);
    acc[1] = (f32x4)(0.f);

    // staging: threads 128..255 -> one A slot each; all threads -> one B slot
    const bool doA = (tid >= 128);
    const int  au  = tid & 127;
    const int  amt = au >> 6;             // A Mtile
    const int  aln = au & 63;             // A frag lane slot
    const float* axsrc =
        x + (size_t)(r0 + amt * 16 + (aln & 15)) * D_MODEL + (aln >> 4) * 8;

    const int bnt = tid >> 6;             // B local ntile 0..3
    const int bln = tid & 63;
    const size_t boff =
        (size_t)(nb * 64 + bnt * 16 + (bln & 15)) * D_MODEL + (bln >> 4) * 8;

    // 2-deep prefetch registers (stage parity = (k0/32)&1)
    float4 a0[2], a1[2];
    int4 pbh[2], pbl[2];
    if (doA) {
        a0[0] = *(const float4*)(axsrc);
        a1[0] = *(const float4*)(axsrc + 4);
        a0[1] = *(const float4*)(axsrc + 32);
        a1[1] = *(const float4*)(axsrc + 36);
    }
    pbh[0] = *(const int4*)(Wh + boff);
    pbl[0] = *(const int4*)(Wl + boff);
    pbh[1] = *(const int4*)(Wh + boff + 32);
    pbl[1] = *(const int4*)(Wl + boff + 32);

    for (int k0 = 0; k0 < D_MODEL; k0 += 32) {
        const int p = (k0 >> 5) & 1;
        __syncthreads();                  // prior iteration's LDS readers done
        // ---- write stage-p registers to LDS
        if (doA) {
            float xv[8];
            *(float4*)&xv[0] = a0[p];
            *(float4*)&xv[4] = a1[p];
            int4 hi, lo;
            split8(xv, hi, lo);
            *(int4*)&Ah[amt * 520 + aln * 8] = hi;
            *(int4*)&Al[amt * 520 + aln * 8] = lo;
        }
        *(int4*)&Bh[bnt * 520 + bln * 8] = pbh[p];
        *(int4*)&Bl[bnt * 520 + bln * 8] = pbl[p];
        __syncthreads();                  // LDS ready
        // ---- refill stage p for k0+64 (consumed two iterations from now)
        const int kn = k0 + 64;
        if (kn < D_MODEL) {
            if (doA) {
                a0[p] = *(const float4*)(axsrc + kn);
                a1[p] = *(const float4*)(axsrc + kn + 4);
            }
            pbh[p] = *(const int4*)(Wh + boff + kn);
            pbl[p] = *(const int4*)(Wl + boff + kn);
        }
        // ---- MFMA: 1 Mtile x 2 Ntiles x 3 split passes
        const bf16x8 afh = *(const bf16x8*)&Ah[mt_w * 520 + lane * 8];
        const bf16x8 afl = *(const bf16x8*)&Al[mt_w * 520 + lane * 8];
        #pragma unroll
        for (int j = 0; j < 2; ++j) {
            const int nt = nt0 + j;
            const bf16x8 bfh = *(const bf16x8*)&Bh[nt * 520 + lane * 8];
            const bf16x8 bfl = *(const bf16x8*)&Bl[nt * 520 + lane * 8];
            acc[j] = __builtin_amdgcn_mfma_f32_16x16x32_bf16(afh, bfh, acc[j], 0, 0, 0);
            acc[j] = __builtin_amdgcn_mfma_f32_16x16x32_bf16(afh, bfl, acc[j], 0, 0, 0);
            acc[j] = __builtin_amdgcn_mfma_f32_16x16x32_bf16(afl, bfh, acc[j], 0, 0, 0);
        }
    }

    // ---- epilogue: C/D layout col=lane&15, row=(lane>>4)*4+reg
    const int rowb = r0 + mt_w * 16 + (lane >> 4) * 4;
    #pragma unroll
    for (int j = 0; j < 2; ++j) {
        const int c = nb * 64 + (nt0 + j) * 16 + (lane & 15);
        if (c < 64) {
            const float bias = bq[c];
            #pragma unroll
            for (int r = 0; r < 4; ++r)
                q[(size_t)(rowb + r) * HS + c] = acc[j][r] + bias;
        } else if (c < 128) {
            const float bias = bk[c - 64];
            #pragma unroll
            for (int r = 0; r < 4; ++r)
                k[(size_t)(rowb + r) * HS + (c - 64)] = acc[j][r] + bias;
        } else {
            float4 o;
            o.x = acc[j][0]; o.y = acc[j][1]; o.z = acc[j][2]; o.w = acc[j][3];
            *(float4*)(vt + (size_t)(c - 128) * BT + rowb) = o;
        }
    }
}

// ---------------------------------------------------------------------------
// Kernel 2: flash-style attention via MFMA — reverted to round-8 version
// (256 threads, 64-row Q-tile, grid (BT/64, 4); part of the 156 µs run).
// ---------------------------------------------------------------------------
__global__ __launch_bounds__(256) void attn_kernel(
    const float* __restrict__ q_ws, const float* __restrict__ k_ws,
    const float* __restrict__ vt_ws, const int* __restrict__ maskp,
    float* __restrict__ part_O, float* __restrict__ part_ml, int BT)
{
    __shared__ __align__(16) short Kh[4096], Kl[4096];
    __shared__ __align__(16) short Vt[4096];
    __shared__ __align__(16) short Pl[4][16 * 72];

    const int tile  = blockIdx.x;
    const int chunk = blockIdx.y;
    const int r0 = tile * 64;
    const int tb = r0 / T_LEN;
    const int t0 = r0 - tb * T_LEN;
    const int mask = (*maskp != 0);
    const int n_max = mask ? (t0 + 64) : T_LEN;
    const int j0 = chunk * JCH;
    if (j0 >= n_max) return;
    const int hi_j = min(j0 + JCH, n_max);
    const int njt = (hi_j - j0 + 63) >> 6;

    const int tid  = threadIdx.x;
    const int w    = tid >> 6;
    const int lane = tid & 63;
    const int quad = lane >> 4;
    const int l15  = lane & 15;
    const int rw0  = t0 + 16 * w;
    const int rowa = r0 + 16 * w + quad * 4;

    bf16x8 qfh[2], qfl[2];
    {
        const float* qrow = q_ws + (size_t)(r0 + 16 * w + l15) * HS + quad * 8;
        #pragma unroll
        for (int kc = 0; kc < 2; ++kc) {
            float v[8];
            *(float4*)&v[0] = *(const float4*)(qrow + kc * 32);
            *(float4*)&v[4] = *(const float4*)(qrow + kc * 32 + 4);
            union { int4 i; bf16x8 b; } ch, cl;
            split8(v, ch.i, cl.i);
            qfh[kc] = ch.b;
            qfl[kc] = cl.b;
        }
    }

    f32x4 oacc[4];
    #pragma unroll
    for (int nt = 0; nt < 4; ++nt) oacc[nt] = (f32x4)(0.f);
    float m_r[4] = {-INFINITY, -INFINITY, -INFINITY, -INFINITY};
    float l_r[4] = {0.f, 0.f, 0.f, 0.f};

    const float* kbase = k_ws + (size_t)tb * T_LEN * HS;

    for (int jt = 0; jt < njt; ++jt) {
        const int jbase = j0 + jt * 64;
        __syncthreads();
        #pragma unroll
        for (int it = 0; it < 2; ++it) {
            const int s  = tid + 256 * it;
            const int ls = s & 63;
            const int sc = s >> 6;
            const int jsub = sc >> 1, kc = sc & 1;
            const int jrow = jbase + jsub * 16 + (ls & 15);
            const int koff = kc * 32 + (ls >> 4) * 8;
            const float* src = kbase + (size_t)jrow * HS + koff;
            float v[8];
            *(float4*)&v[0] = *(const float4*)src;
            *(float4*)&v[4] = *(const float4*)(src + 4);
            int4 hi, lo;
            split8(v, hi, lo);
            *(int4*)&Kh[s * 8] = hi;
            *(int4*)&Kl[s * 8] = lo;
        }
        #pragma unroll
        for (int it = 0; it < 2; ++it) {
            const int s  = tid + 256 * it;
            const int ls = s & 63;
            const int sc = s >> 6;
            const int jc = sc >> 2, nt = sc & 3;
            const int n  = nt * 16 + (ls & 15);
            const int jcol = jbase + jc * 32 + (ls >> 4) * 8;
            const float* src = vt_ws + (size_t)n * BT + tb * T_LEN + jcol;
            float v[8];
            *(float4*)&v[0] = *(const float4*)src;
            *(float4*)&v[4] = *(const float4*)(src + 4);
            union { unsigned short u[8]; int4 i; } pk;
            #pragma unroll
            for (int i = 0; i < 8; ++i) pk.u[i] = f2bf_rne(v[i]);
            *(int4*)&Vt[s * 8] = pk.i;
        }
        __syncthreads();

        const bool active = (!mask) || (jbase <= rw0 + 15);
        if (active) {
            f32x4 sacc[4];
            #pragma unroll
            for (int jsub = 0; jsub < 4; ++jsub) {
                f32x4 s = (f32x4)(0.f);
                #pragma unroll
                for (int kc = 0; kc < 2; ++kc) {
                    const bf16x8 kh = *(const bf16x8*)&Kh[((jsub * 2 + kc) * 64 + lane) * 8];
                    const bf16x8 kl = *(const bf16x8*)&Kl[((jsub * 2 + kc) * 64 + lane) * 8];
                    s = __builtin_amdgcn_mfma_f32_16x16x32_bf16(qfh[kc], kh, s, 0, 0, 0);
                    s = __builtin_amdgcn_mfma_f32_16x16x32_bf16(qfh[kc], kl, s, 0, 0, 0);
                    s = __builtin_amdgcn_mfma_f32_16x16x32_bf16(qfl[kc], kh, s, 0, 0, 0);
                }
                sacc[jsub] = s;
            }
            float sval[4][4], rmax[4];
            #pragma unroll
            for (int r = 0; r < 4; ++r) rmax[r] = -INFINITY;
            #pragma unroll
            for (int jsub = 0; jsub < 4; ++jsub) {
                const int jg = jbase + jsub * 16 + l15;
                #pragma unroll
                for (int r = 0; r < 4; ++r) {
                    const int tg = rw0 + quad * 4 + r;
                    const float vv = (mask && (jg > tg)) ? -INFINITY : 8.0f * sacc[jsub][r];
                    sval[jsub][r] = vv;
                    rmax[r] = fmaxf(rmax[r], vv);
                }
            }
            #pragma unroll
            for (int d = 1; d < 16; d <<= 1)
                #pragma unroll
                for (int r = 0; r < 4; ++r)
                    rmax[r] = fmaxf(rmax[r], __shfl_xor(rmax[r], d));
            float alpha[4], msafe[4];
            #pragma unroll
            for (int r = 0; r < 4; ++r) {
                const float mn = fmaxf(m_r[r], rmax[r]);
                msafe[r] = (mn == -INFINITY) ? 0.f : mn;
                alpha[r] = __expf(m_r[r] - msafe[r]);
                m_r[r] = mn;
            }
            short* Pw = &Pl[w][0];
            float rsum[4] = {0.f, 0.f, 0.f, 0.f};
            #pragma unroll
            for (int jsub = 0; jsub < 4; ++jsub) {
                #pragma unroll
                for (int r = 0; r < 4; ++r) {
                    const float e = __expf(sval[jsub][r] - msafe[r]);
                    const unsigned short eb = f2bf_rne(e);
                    Pw[(quad * 4 + r) * 72 + jsub * 16 + l15] = (short)eb;
                    rsum[r] += bf2f(eb);
                }
            }
            #pragma unroll
            for (int d = 1; d < 16; d <<= 1)
                #pragma unroll
                for (int r = 0; r < 4; ++r)
                    rsum[r] += __shfl_xor(rsum[r], d);
            #pragma unroll
            for (int r = 0; r < 4; ++r)
                l_r[r] = l_r[r] * alpha[r] + rsum[r];
            #pragma unroll
            for (int nt = 0; nt < 4; ++nt)
                #pragma unroll
                for (int r = 0; r < 4; ++r)
                    oacc[nt][r] *= alpha[r];
            bf16x8 pf[2];
            #pragma unroll
            for (int jc = 0; jc < 2; ++jc)
                pf[jc] = *(const bf16x8*)&Pw[l15 * 72 + jc * 32 + quad * 8];
            #pragma unroll
            for (int nt = 0; nt < 4; ++nt) {
                #pragma unroll
                for (int jc = 0; jc < 2; ++jc) {
                    const bf16x8 vf = *(const bf16x8*)&Vt[((jc * 4 + nt) * 64 + lane) * 8];
                    oacc[nt] = __builtin_amdgcn_mfma_f32_16x16x32_bf16(pf[jc], vf, oacc[nt], 0, 0, 0);
                }
            }
        }
    }

    #pragma unroll
    for (int nt = 0; nt < 4; ++nt)
        #pragma unroll
        for (int r = 0; r < 4; ++r)
            part_O[((size_t)(rowa + r) * NCH + chunk) * HS + nt * 16 + l15] = oacc[nt][r];
    if (l15 == 0) {
        #pragma unroll
        for (int r = 0; r < 4; ++r) {
            float2 ml;
            ml.x = m_r[r];
            ml.y = l_r[r];
            *(float2*)(part_ml + ((size_t)(rowa + r) * NCH + chunk) * 2) = ml;
        }
    }
}

// ---------------------------------------------------------------------------
// Kernel 3: combine chunk partials — UNCHANGED (passing).
// ---------------------------------------------------------------------------
__global__ __launch_bounds__(256) void combine_kernel(
    const float* __restrict__ part_O, const float* __restrict__ part_ml,
    const int* __restrict__ maskp, float* __restrict__ out)
{
    const int f = blockIdx.x * 256 + threadIdx.x;
    const int row = f >> 6;
    const int d = f & 63;
    const int t = row & (T_LEN - 1);
    const int mask = (*maskp != 0);
    const int n = mask ? (t + 1) : T_LEN;
    const int nc = (n + JCH - 1) / JCH;

    float mv[NCH], lv[NCH];
    float M = -INFINITY;
    for (int c = 0; c < nc; ++c) {
        const float2 ml = *(const float2*)(part_ml + ((size_t)row * NCH + c) * 2);
        mv[c] = ml.x; lv[c] = ml.y;
        M = fmaxf(M, ml.x);
    }
    float L = 0.f, O = 0.f;
    for (int c = 0; c < nc; ++c) {
        const float w = __expf(mv[c] - M);
        L += lv[c] * w;
        O = fmaf(part_O[((size_t)row * NCH + c) * HS + d], w, O);
    }
    out[(size_t)row * HS + d] = O / L;
}

// ---------------------------------------------------------------------------
extern "C" void kernel_launch(void* const* d_in, const int* in_sizes, int n_in,
                              void* d_out, int out_size, void* d_ws, size_t ws_size,
                              hipStream_t stream) {
    const float* x  = (const float*)d_in[0];
    const float* Wq = (const float*)d_in[1];
    const float* bq = (const float*)d_in[2];
    const float* Wk = (const float*)d_in[3];
    const float* bk = (const float*)d_in[4];
    const float* Wv = (const float*)d_in[5];
    const int* maskp = (const int*)d_in[6];

    const int BT = in_sizes[0] / D_MODEL;   // 8192

    // ws layout (floats): q,k [BT*64], vt [64*BT], part_O [BT*4*64], part_ml [BT*4*2]
    float* q   = (float*)d_ws;
    float* k   = q + (size_t)BT * HS;
    float* vt  = k + (size_t)BT * HS;
    float* pO  = vt + (size_t)BT * HS;
    float* pml = pO + (size_t)BT * NCH * HS;

    // W split buffers ALIAS part_O (dead until attn_kernel runs, stream-ordered)
    short* Wh = (short*)pO;
    short* Wl = Wh + (size_t)192 * D_MODEL;

    wprep_kernel<<<48, 256, 0, stream>>>(Wq, Wk, Wv, Wh, Wl);
    dim3 qgrid(BT / 32, 3);
    qkv_kernel<<<qgrid, 256, 0, stream>>>(x, Wh, Wl, bq, bk, q, k, vt, BT);
    dim3 agrid(BT / 64, NCH);
    attn_kernel<<<agrid, 256, 0, stream>>>(q, k, vt, maskp, pO, pml, BT);
    combine_kernel<<<(BT * HS) / 256, 256, 0, stream>>>(pO, pml, maskp, (float*)d_out);
}

// Round 11
// 151.153 us; speedup vs baseline: 1.6562x; 1.2923x over previous
//
#include <hip/hip_runtime.h>
#include <hip/hip_bf16.h>

// AttentionHead: B=4, T=2048, C=1024, hs=64. All fp32 in/out.
#define D_MODEL 1024
#define HS 64
#define T_LEN 2048
#define JCH 512          // j-chunk width per attention block
#define NCH 4            // max chunks per row = T_LEN/JCH

typedef __attribute__((ext_vector_type(8))) short bf16x8;   // MFMA A/B frag
typedef __attribute__((ext_vector_type(4))) float f32x4;    // MFMA C/D frag

// split 8 floats into hi/lo bf16 (truncation split: residual exact)
__device__ inline void split8(const float* v, int4& hi, int4& lo) {
    union { unsigned short u[8]; int4 v4; } uh, ul;
    #pragma unroll
    for (int i = 0; i < 8; ++i) {
        const unsigned int b = __float_as_uint(v[i]);
        const unsigned short h = (unsigned short)(b >> 16);
        const float r = v[i] - __uint_as_float((unsigned int)h << 16);
        uh.u[i] = h;
        ul.u[i] = (unsigned short)(__float_as_uint(r) >> 16);
    }
    hi = uh.v4; lo = ul.v4;
}

// fp32 -> bf16 round-to-nearest-even (finite inputs only here)
__device__ inline unsigned short f2bf_rne(float f) {
    const unsigned int b = __float_as_uint(f);
    return (unsigned short)((b + 0x7FFFu + ((b >> 16) & 1u)) >> 16);
}
__device__ inline float bf2f(unsigned short h) {
    return __uint_as_float((unsigned int)h << 16);
}

// ---------------------------------------------------------------------------
// Kernel 0: W prep (coalesced) — UNCHANGED (passing).
// ---------------------------------------------------------------------------
__global__ __launch_bounds__(256) void wprep_kernel(
    const float* __restrict__ Wq, const float* __restrict__ Wk,
    const float* __restrict__ Wv, short* __restrict__ Wh, short* __restrict__ Wl)
{
    __shared__ float tile[64][69];
    const int tid = threadIdx.x;
    const int kb = blockIdx.x & 15;       // k-block 0..15
    const int m  = blockIdx.x >> 4;       // matrix 0..2
    const float* W = (m == 0) ? Wq : (m == 1) ? Wk : Wv;
    #pragma unroll
    for (int it = 0; it < 4; ++it) {
        const int idx = tid + 256 * it;
        const int kr = idx >> 4, c4 = idx & 15;
        *(float4*)&tile[kr][4 * c4] =
            *(const float4*)(W + (size_t)(kb * 64 + kr) * HS + 4 * c4);
    }
    __syncthreads();
    #pragma unroll
    for (int it = 0; it < 2; ++it) {
        const int s = tid + 256 * it;     // 0..511
        const int n = s >> 3, kc = s & 7;
        float v[8];
        #pragma unroll
        for (int i = 0; i < 8; ++i) v[i] = tile[kc * 8 + i][n];
        int4 hi, lo;
        split8(v, hi, lo);
        const size_t off = (size_t)(m * 64 + n) * D_MODEL + kb * 64 + kc * 8;
        *(int4*)(Wh + off) = hi;
        *(int4*)(Wl + off) = lo;
    }
}

// ---------------------------------------------------------------------------
// Kernel 1: QKV projection via split-bf16 MFMA.
// Grid (BT/32, 3) = 768 blocks x 256 threads -> 3 blocks/CU. Tile 32 M x
// 64 N; wave = 1 Mtile x 2 Ntiles. Column slice nb aligns exactly with
// q / k / vt (one block owns every 128B output line).
// Pipeline: 1-deep register prefetch in PLAIN SCALAR registers.
// NOTE: round 10's 2-deep prefetch used runtime-indexed arrays (a0[p]...)
// which the compiler allocated to SCRATCH -> ~77 MB of HBM write traffic
// (per-thread spill state), 12x write amplification. No register arrays
// with runtime indices allowed here.
// ---------------------------------------------------------------------------
__global__ __launch_bounds__(256, 2) void qkv_kernel(
    const float* __restrict__ x,
    const short* __restrict__ Wh, const short* __restrict__ Wl,
    const float* __restrict__ bq, const float* __restrict__ bk,
    float* __restrict__ q, float* __restrict__ k, float* __restrict__ vt, int BT)
{
    __shared__ __align__(16) short Ah[2 * 520], Al[2 * 520];   // 2 Mtiles
    __shared__ __align__(16) short Bh[4 * 520], Bl[4 * 520];   // 4 Ntiles

    const int tid  = threadIdx.x;
    const int r0   = blockIdx.x * 32;
    const int nb   = blockIdx.y;          // col slice: global cols 64*nb ..
    const int wave = tid >> 6;
    const int lane = tid & 63;
    const int mt_w = wave >> 1;           // wave's Mtile (0..1)
    const int nt0  = (wave & 1) * 2;      // wave's first local ntile

    f32x4 acc0 = (f32x4)(0.f);
    f32x4 acc1 = (f32x4)(0.f);

    // staging: threads 128..255 -> one A slot each; all threads -> one B slot
    const bool doA = (tid >= 128);
    const int  au  = tid & 127;
    const int  amt = au >> 6;             // A Mtile
    const int  aln = au & 63;             // A frag lane slot
    const float* axsrc =
        x + (size_t)(r0 + amt * 16 + (aln & 15)) * D_MODEL + (aln >> 4) * 8;

    const int bnt = tid >> 6;             // B local ntile 0..3
    const int bln = tid & 63;
    const size_t boff =
        (size_t)(nb * 64 + bnt * 16 + (bln & 15)) * D_MODEL + (bln >> 4) * 8;

    // 1-deep prefetch in scalar registers
    float4 a0v, a1v;
    int4 pbh, pbl;
    if (doA) {
        a0v = *(const float4*)(axsrc);
        a1v = *(const float4*)(axsrc + 4);
    }
    pbh = *(const int4*)(Wh + boff);
    pbl = *(const int4*)(Wl + boff);

    for (int k0 = 0; k0 < D_MODEL; k0 += 32) {
        __syncthreads();                  // prior iteration's LDS readers done
        // ---- write staged registers to LDS
        if (doA) {
            float xv[8];
            *(float4*)&xv[0] = a0v;
            *(float4*)&xv[4] = a1v;
            int4 hi, lo;
            split8(xv, hi, lo);
            *(int4*)&Ah[amt * 520 + aln * 8] = hi;
            *(int4*)&Al[amt * 520 + aln * 8] = lo;
        }
        *(int4*)&Bh[bnt * 520 + bln * 8] = pbh;
        *(int4*)&Bl[bnt * 520 + bln * 8] = pbl;
        __syncthreads();                  // LDS ready
        // ---- preload next k-chunk (latency hides under MFMA below)
        const int kn = k0 + 32;
        if (kn < D_MODEL) {
            if (doA) {
                a0v = *(const float4*)(axsrc + kn);
                a1v = *(const float4*)(axsrc + kn + 4);
            }
            pbh = *(const int4*)(Wh + boff + kn);
            pbl = *(const int4*)(Wl + boff + kn);
        }
        // ---- MFMA: 1 Mtile x 2 Ntiles x 3 split passes
        const bf16x8 afh = *(const bf16x8*)&Ah[mt_w * 520 + lane * 8];
        const bf16x8 afl = *(const bf16x8*)&Al[mt_w * 520 + lane * 8];
        {
            const bf16x8 bfh = *(const bf16x8*)&Bh[nt0 * 520 + lane * 8];
            const bf16x8 bfl = *(const bf16x8*)&Bl[nt0 * 520 + lane * 8];
            acc0 = __builtin_amdgcn_mfma_f32_16x16x32_bf16(afh, bfh, acc0, 0, 0, 0);
            acc0 = __builtin_amdgcn_mfma_f32_16x16x32_bf16(afh, bfl, acc0, 0, 0, 0);
            acc0 = __builtin_amdgcn_mfma_f32_16x16x32_bf16(afl, bfh, acc0, 0, 0, 0);
        }
        {
            const bf16x8 bfh = *(const bf16x8*)&Bh[(nt0 + 1) * 520 + lane * 8];
            const bf16x8 bfl = *(const bf16x8*)&Bl[(nt0 + 1) * 520 + lane * 8];
            acc1 = __builtin_amdgcn_mfma_f32_16x16x32_bf16(afh, bfh, acc1, 0, 0, 0);
            acc1 = __builtin_amdgcn_mfma_f32_16x16x32_bf16(afh, bfl, acc1, 0, 0, 0);
            acc1 = __builtin_amdgcn_mfma_f32_16x16x32_bf16(afl, bfh, acc1, 0, 0, 0);
        }
    }

    // ---- epilogue: C/D layout col=lane&15, row=(lane>>4)*4+reg
    const int rowb = r0 + mt_w * 16 + (lane >> 4) * 4;
    #pragma unroll
    for (int j = 0; j < 2; ++j) {
        const f32x4 a = (j == 0) ? acc0 : acc1;
        const int c = nb * 64 + (nt0 + j) * 16 + (lane & 15);
        if (c < 64) {
            const float bias = bq[c];
            #pragma unroll
            for (int r = 0; r < 4; ++r)
                q[(size_t)(rowb + r) * HS + c] = a[r] + bias;
        } else if (c < 128) {
            const float bias = bk[c - 64];
            #pragma unroll
            for (int r = 0; r < 4; ++r)
                k[(size_t)(rowb + r) * HS + (c - 64)] = a[r] + bias;
        } else {
            float4 o;
            o.x = a[0]; o.y = a[1]; o.z = a[2]; o.w = a[3];
            *(float4*)(vt + (size_t)(c - 128) * BT + rowb) = o;
        }
    }
}

// ---------------------------------------------------------------------------
// Kernel 2: flash-style attention via MFMA — round-8 version, UNCHANGED
// (256 threads, 64-row Q-tile, grid (BT/64, 4); part of the 156 µs run).
// ---------------------------------------------------------------------------
__global__ __launch_bounds__(256) void attn_kernel(
    const float* __restrict__ q_ws, const float* __restrict__ k_ws,
    const float* __restrict__ vt_ws, const int* __restrict__ maskp,
    float* __restrict__ part_O, float* __restrict__ part_ml, int BT)
{
    __shared__ __align__(16) short Kh[4096], Kl[4096];
    __shared__ __align__(16) short Vt[4096];
    __shared__ __align__(16) short Pl[4][16 * 72];

    const int tile  = blockIdx.x;
    const int chunk = blockIdx.y;
    const int r0 = tile * 64;
    const int tb = r0 / T_LEN;
    const int t0 = r0 - tb * T_LEN;
    const int mask = (*maskp != 0);
    const int n_max = mask ? (t0 + 64) : T_LEN;
    const int j0 = chunk * JCH;
    if (j0 >= n_max) return;
    const int hi_j = min(j0 + JCH, n_max);
    const int njt = (hi_j - j0 + 63) >> 6;

    const int tid  = threadIdx.x;
    const int w    = tid >> 6;
    const int lane = tid & 63;
    const int quad = lane >> 4;
    const int l15  = lane & 15;
    const int rw0  = t0 + 16 * w;
    const int rowa = r0 + 16 * w + quad * 4;

    bf16x8 qfh[2], qfl[2];
    {
        const float* qrow = q_ws + (size_t)(r0 + 16 * w + l15) * HS + quad * 8;
        #pragma unroll
        for (int kc = 0; kc < 2; ++kc) {
            float v[8];
            *(float4*)&v[0] = *(const float4*)(qrow + kc * 32);
            *(float4*)&v[4] = *(const float4*)(qrow + kc * 32 + 4);
            union { int4 i; bf16x8 b; } ch, cl;
            split8(v, ch.i, cl.i);
            qfh[kc] = ch.b;
            qfl[kc] = cl.b;
        }
    }

    f32x4 oacc[4];
    #pragma unroll
    for (int nt = 0; nt < 4; ++nt) oacc[nt] = (f32x4)(0.f);
    float m_r[4] = {-INFINITY, -INFINITY, -INFINITY, -INFINITY};
    float l_r[4] = {0.f, 0.f, 0.f, 0.f};

    const float* kbase = k_ws + (size_t)tb * T_LEN * HS;

    for (int jt = 0; jt < njt; ++jt) {
        const int jbase = j0 + jt * 64;
        __syncthreads();
        #pragma unroll
        for (int it = 0; it < 2; ++it) {
            const int s  = tid + 256 * it;
            const int ls = s & 63;
            const int sc = s >> 6;
            const int jsub = sc >> 1, kc = sc & 1;
            const int jrow = jbase + jsub * 16 + (ls & 15);
            const int koff = kc * 32 + (ls >> 4) * 8;
            const float* src = kbase + (size_t)jrow * HS + koff;
            float v[8];
            *(float4*)&v[0] = *(const float4*)src;
            *(float4*)&v[4] = *(const float4*)(src + 4);
            int4 hi, lo;
            split8(v, hi, lo);
            *(int4*)&Kh[s * 8] = hi;
            *(int4*)&Kl[s * 8] = lo;
        }
        #pragma unroll
        for (int it = 0; it < 2; ++it) {
            const int s  = tid + 256 * it;
            const int ls = s & 63;
            const int sc = s >> 6;
            const int jc = sc >> 2, nt = sc & 3;
            const int n  = nt * 16 + (ls & 15);
            const int jcol = jbase + jc * 32 + (ls >> 4) * 8;
            const float* src = vt_ws + (size_t)n * BT + tb * T_LEN + jcol;
            float v[8];
            *(float4*)&v[0] = *(const float4*)src;
            *(float4*)&v[4] = *(const float4*)(src + 4);
            union { unsigned short u[8]; int4 i; } pk;
            #pragma unroll
            for (int i = 0; i < 8; ++i) pk.u[i] = f2bf_rne(v[i]);
            *(int4*)&Vt[s * 8] = pk.i;
        }
        __syncthreads();

        const bool active = (!mask) || (jbase <= rw0 + 15);
        if (active) {
            f32x4 sacc[4];
            #pragma unroll
            for (int jsub = 0; jsub < 4; ++jsub) {
                f32x4 s = (f32x4)(0.f);
                #pragma unroll
                for (int kc = 0; kc < 2; ++kc) {
                    const bf16x8 kh = *(const bf16x8*)&Kh[((jsub * 2 + kc) * 64 + lane) * 8];
                    const bf16x8 kl = *(const bf16x8*)&Kl[((jsub * 2 + kc) * 64 + lane) * 8];
                    s = __builtin_amdgcn_mfma_f32_16x16x32_bf16(qfh[kc], kh, s, 0, 0, 0);
                    s = __builtin_amdgcn_mfma_f32_16x16x32_bf16(qfh[kc], kl, s, 0, 0, 0);
                    s = __builtin_amdgcn_mfma_f32_16x16x32_bf16(qfl[kc], kh, s, 0, 0, 0);
                }
                sacc[jsub] = s;
            }
            float sval[4][4], rmax[4];
            #pragma unroll
            for (int r = 0; r < 4; ++r) rmax[r] = -INFINITY;
            #pragma unroll
            for (int jsub = 0; jsub < 4; ++jsub) {
                const int jg = jbase + jsub * 16 + l15;
                #pragma unroll
                for (int r = 0; r < 4; ++r) {
                    const int tg = rw0 + quad * 4 + r;
                    const float vv = (mask && (jg > tg)) ? -INFINITY : 8.0f * sacc[jsub][r];
                    sval[jsub][r] = vv;
                    rmax[r] = fmaxf(rmax[r], vv);
                }
            }
            #pragma unroll
            for (int d = 1; d < 16; d <<= 1)
                #pragma unroll
                for (int r = 0; r < 4; ++r)
                    rmax[r] = fmaxf(rmax[r], __shfl_xor(rmax[r], d));
            float alpha[4], msafe[4];
            #pragma unroll
            for (int r = 0; r < 4; ++r) {
                const float mn = fmaxf(m_r[r], rmax[r]);
                msafe[r] = (mn == -INFINITY) ? 0.f : mn;
                alpha[r] = __expf(m_r[r] - msafe[r]);
                m_r[r] = mn;
            }
            short* Pw = &Pl[w][0];
            float rsum[4] = {0.f, 0.f, 0.f, 0.f};
            #pragma unroll
            for (int jsub = 0; jsub < 4; ++jsub) {
                #pragma unroll
                for (int r = 0; r < 4; ++r) {
                    const float e = __expf(sval[jsub][r] - msafe[r]);
                    const unsigned short eb = f2bf_rne(e);
                    Pw[(quad * 4 + r) * 72 + jsub * 16 + l15] = (short)eb;
                    rsum[r] += bf2f(eb);
                }
            }
            #pragma unroll
            for (int d = 1; d < 16; d <<= 1)
                #pragma unroll
                for (int r = 0; r < 4; ++r)
                    rsum[r] += __shfl_xor(rsum[r], d);
            #pragma unroll
            for (int r = 0; r < 4; ++r)
                l_r[r] = l_r[r] * alpha[r] + rsum[r];
            #pragma unroll
            for (int nt = 0; nt < 4; ++nt)
                #pragma unroll
                for (int r = 0; r < 4; ++r)
                    oacc[nt][r] *= alpha[r];
            bf16x8 pf[2];
            #pragma unroll
            for (int jc = 0; jc < 2; ++jc)
                pf[jc] = *(const bf16x8*)&Pw[l15 * 72 + jc * 32 + quad * 8];
            #pragma unroll
            for (int nt = 0; nt < 4; ++nt) {
                #pragma unroll
                for (int jc = 0; jc < 2; ++jc) {
                    const bf16x8 vf = *(const bf16x8*)&Vt[((jc * 4 + nt) * 64 + lane) * 8];
                    oacc[nt] = __builtin_amdgcn_mfma_f32_16x16x32_bf16(pf[jc], vf, oacc[nt], 0, 0, 0);
                }
            }
        }
    }

    #pragma unroll
    for (int nt = 0; nt < 4; ++nt)
        #pragma unroll
        for (int r = 0; r < 4; ++r)
            part_O[((size_t)(rowa + r) * NCH + chunk) * HS + nt * 16 + l15] = oacc[nt][r];
    if (l15 == 0) {
        #pragma unroll
        for (int r = 0; r < 4; ++r) {
            float2 ml;
            ml.x = m_r[r];
            ml.y = l_r[r];
            *(float2*)(part_ml + ((size_t)(rowa + r) * NCH + chunk) * 2) = ml;
        }
    }
}

// ---------------------------------------------------------------------------
// Kernel 3: combine chunk partials — UNCHANGED (passing).
// ---------------------------------------------------------------------------
__global__ __launch_bounds__(256) void combine_kernel(
    const float* __restrict__ part_O, const float* __restrict__ part_ml,
    const int* __restrict__ maskp, float* __restrict__ out)
{
    const int f = blockIdx.x * 256 + threadIdx.x;
    const int row = f >> 6;
    const int d = f & 63;
    const int t = row & (T_LEN - 1);
    const int mask = (*maskp != 0);
    const int n = mask ? (t + 1) : T_LEN;
    const int nc = (n + JCH - 1) / JCH;

    float mv[NCH], lv[NCH];
    float M = -INFINITY;
    for (int c = 0; c < nc; ++c) {
        const float2 ml = *(const float2*)(part_ml + ((size_t)row * NCH + c) * 2);
        mv[c] = ml.x; lv[c] = ml.y;
        M = fmaxf(M, ml.x);
    }
    float L = 0.f, O = 0.f;
    for (int c = 0; c < nc; ++c) {
        const float w = __expf(mv[c] - M);
        L += lv[c] * w;
        O = fmaf(part_O[((size_t)row * NCH + c) * HS + d], w, O);
    }
    out[(size_t)row * HS + d] = O / L;
}

// ---------------------------------------------------------------------------
extern "C" void kernel_launch(void* const* d_in, const int* in_sizes, int n_in,
                              void* d_out, int out_size, void* d_ws, size_t ws_size,
                              hipStream_t stream) {
    const float* x  = (const float*)d_in[0];
    const float* Wq = (const float*)d_in[1];
    const float* bq = (const float*)d_in[2];
    const float* Wk = (const float*)d_in[3];
    const float* bk = (const float*)d_in[4];
    const float* Wv = (const float*)d_in[5];
    const int* maskp = (const int*)d_in[6];

    const int BT = in_sizes[0] / D_MODEL;   // 8192

    // ws layout (floats): q,k [BT*64], vt [64*BT], part_O [BT*4*64], part_ml [BT*4*2]
    float* q   = (float*)d_ws;
    float* k   = q + (size_t)BT * HS;
    float* vt  = k + (size_t)BT * HS;
    float* pO  = vt + (size_t)BT * HS;
    float* pml = pO + (size_t)BT * NCH * HS;

    // W split buffers ALIAS part_O (dead until attn_kernel runs, stream-ordered)
    short* Wh = (short*)pO;
    short* Wl = Wh + (size_t)192 * D_MODEL;

    wprep_kernel<<<48, 256, 0, stream>>>(Wq, Wk, Wv, Wh, Wl);
    dim3 qgrid(BT / 32, 3);
    qkv_kernel<<<qgrid, 256, 0, stream>>>(x, Wh, Wl, bq, bk, q, k, vt, BT);
    dim3 agrid(BT / 64, NCH);
    attn_kernel<<<agrid, 256, 0, stream>>>(q, k, vt, maskp, pO, pml, BT);
    combine_kernel<<<(BT * HS) / 256, 256, 0, stream>>>(pO, pml, maskp, (float*)d_out);
}